// Round 8
// baseline (11380.270 us; speedup 1.0000x reference)
//
#include <hip/hip_runtime.h>
#include <hip/hip_bf16.h>
#include <math.h>

#define E_DIM 1024
#define FF_DIM 4096
#define LAYERS 24
#define MPAD 320      // 20 * 16 token-row padding (rows 257..319 zero / ignored)
#define SPAD 288      // vT / P column padding (9 * 32)
#define KCP 608       // conv K (588) padded to 19*32
#define NB 256        // persistent grid blocks (1/CU => co-resident)

typedef __attribute__((ext_vector_type(8))) short short8;
typedef __attribute__((ext_vector_type(8))) __bf16 bf16x8;
typedef __attribute__((ext_vector_type(4))) float float4_t;
typedef __attribute__((ext_vector_type(4))) unsigned short ushort4_t;

union ABu { short8 s; bf16x8 b; };
union BFU { __bf16 b; unsigned short u; };

__device__ __forceinline__ float4_t MFMA(bf16x8 a, bf16x8 b, float4_t c) {
  return __builtin_amdgcn_mfma_f32_16x16x32_bf16(a, b, c, 0, 0, 0);
}
__device__ __forceinline__ float4_t MFMAs(short8 a, short8 b, float4_t c) {
  ABu ua, ub; ua.s = a; ub.s = b;
  return __builtin_amdgcn_mfma_f32_16x16x32_bf16(ua.b, ub.b, c, 0, 0, 0);
}
__device__ __forceinline__ unsigned short f2bf(float f) {
  BFU x; x.b = (__bf16)f; return x.u;
}

// async global->LDS: 16B per lane, LDS dest = wave-uniform base + lane*16
__device__ __forceinline__ void glds16(const float* src, float* dst) {
  __builtin_amdgcn_global_load_lds(
      (const __attribute__((address_space(1))) unsigned int*)src,
      (__attribute__((address_space(3))) unsigned int*)dst, 16, 0, 0);
}

struct MegaParams {
  const float *frame, *bboxes, *conv_w, *cls_emb;
  const float *ln1_s, *ln1_b;
  const float *wq, *bq, *wk, *bk, *wv, *bv, *wo, *bo;
  const float *ln2_s, *ln2_b, *w1, *b1, *w2, *b2;
  float* x;
  unsigned short *h, *qb, *kb, *vT, *ob, *mb;
  float *part, *pbv, *Mi;
  unsigned short *Pm, *Wp;
  float* out;
  unsigned* bar;
};

// ---------------------------------------------------------------------------
// Barrier v3: slot-write + sweeper. No same-line RMW contention.
//  - leader of block b STOREs gen g to slot bar[b*32] (128B apart)
//  - block 0's 256 threads sweep all slots in parallel until all >= g
//  - block 0 leader stores g to broadcast line bar[8192]
//  - other leaders poll broadcast (read-only line) with s_sleep backoff
// Monotone g (caller increments); memset once per kernel_launch.
// ---------------------------------------------------------------------------
__device__ __forceinline__ void gsync(unsigned* bar, int bid, unsigned g) {
  __threadfence();   // release: data writes reach coherence point first
  __syncthreads();
  if (bid == 0) {
    if (threadIdx.x == 0)
      __hip_atomic_store(bar, g, __ATOMIC_RELAXED, __HIP_MEMORY_SCOPE_AGENT);
    unsigned* slot = bar + (int)threadIdx.x * 32;
    while (__hip_atomic_load(slot, __ATOMIC_RELAXED, __HIP_MEMORY_SCOPE_AGENT) < g)
      __builtin_amdgcn_s_sleep(1);
    __syncthreads();   // all 256 slots seen
    if (threadIdx.x == 0)
      __hip_atomic_store(bar + 8192, g, __ATOMIC_RELAXED, __HIP_MEMORY_SCOPE_AGENT);
  } else {
    if (threadIdx.x == 0) {
      __hip_atomic_store(bar + bid * 32, g, __ATOMIC_RELAXED, __HIP_MEMORY_SCOPE_AGENT);
      while (__hip_atomic_load(bar + 8192, __ATOMIC_RELAXED, __HIP_MEMORY_SCOPE_AGENT) < g)
        __builtin_amdgcn_s_sleep(8);
    }
  }
  __syncthreads();
  __threadfence();   // acquire: invalidate caches once
}

// ---------------------------------------------------------------------------
// prep: im2col, conv-weight repack, pad zeroing — grid-stride
// ---------------------------------------------------------------------------
__device__ void phase_prep(const MegaParams& P, int gtid) {
  for (int i = gtid; i < 256 * KCP; i += NB * 256) {
    int b = i / KCP, kk = i - b * KCP;
    unsigned short us = 0;
    if (kk < 588) {
      int c = kk / 196, rem = kk % 196;
      int pr = b >> 4, pc = b & 15;
      int ii = rem / 14, jj = rem % 14;
      us = f2bf(P.frame[c * 224 * 224 + (pr * 14 + ii) * 224 + (pc * 14 + jj)]);
    }
    P.Pm[i] = us;
  }
  for (int i = gtid; i < 1024 * KCP; i += NB * 256) {
    int n = i / KCP, kk = i - n * KCP;
    P.Wp[i] = (kk < 588) ? f2bf(P.conv_w[n * 588 + kk]) : (unsigned short)0;
  }
  const int NH = (MPAD - 257) * E_DIM;
  const int NO = (MPAD - 272) * E_DIM;
  const int NV = 16 * 64 * (SPAD - 272);
  for (int i = gtid; i < NH + NO + NV; i += NB * 256) {
    if (i < NH) P.h[257 * E_DIM + i] = 0;
    else if (i < NH + NO) P.ob[272 * E_DIM + (i - NH)] = 0;
    else {
      int k = i - NH - NO;
      P.vT[(size_t)(k >> 4) * SPAD + 272 + (k & 15)] = 0;
    }
  }
}

// ---------------------------------------------------------------------------
// pb_cls (one block)
// ---------------------------------------------------------------------------
__device__ void phase_pbcls(const MegaParams& P, char* smem, int tid) {
  float* sb = (float*)smem;
  float* red = sb + 128;
  if (tid < 128) sb[tid] = P.bboxes[tid];
  __syncthreads();
  int p = tid;
  float px1 = (float)((p & 15) * 14), py1 = (float)((p >> 4) * 14);
  float px2 = px1 + 14.f, py2 = py1 + 14.f;
  float s = 0.f;
  for (int r = 0; r < 32; ++r) {
    float bx1 = sb[r * 4 + 0], by1 = sb[r * 4 + 1], bx2 = sb[r * 4 + 2], by2 = sb[r * 4 + 3];
    float iw = fmaxf(fminf(bx2, px2) - fmaxf(bx1, px1), 0.f);
    float ih = fmaxf(fminf(by2, py2) - fmaxf(by1, py1), 0.f);
    float ov = iw * ih * (1.f / 196.f);
    P.Mi[r * 256 + p] = ov;
    s += ov;
  }
  red[tid] = s;
  __syncthreads();
  for (int off = 128; off > 0; off >>= 1) {
    if (tid < off) red[tid] = fmaxf(red[tid], red[tid + off]);
    __syncthreads();
  }
  P.pbv[p] = s / (red[0] + 1e-6f);
  for (int j = 0; j < 4; ++j) P.x[tid * 4 + j] = P.cls_emb[tid * 4 + j];
}

// ---------------------------------------------------------------------------
// conv GEMM (items 0..63)
// ---------------------------------------------------------------------------
__device__ void phase_conv(const MegaParams& P, int vb, int tid) {
  int n0 = vb * 16;
  int wave = tid >> 6, lane = tid & 63;
  int lg = lane >> 4, lc = lane & 15;
  float4_t acc[4] = {{0,0,0,0},{0,0,0,0},{0,0,0,0},{0,0,0,0}};
  const unsigned short* bp = P.Wp + (size_t)(n0 + lc) * KCP + lg * 8;
  const unsigned short* apt[4];
#pragma unroll
  for (int t = 0; t < 4; ++t) apt[t] = P.Pm + (size_t)((wave + t * 4) * 16 + lc) * KCP + lg * 8;
  for (int s = 0; s < 19; ++s) {
    short8 bf = *(const short8*)bp; bp += 32;
#pragma unroll
    for (int t = 0; t < 4; ++t) {
      short8 af = *(const short8*)apt[t]; apt[t] += 32;
      acc[t] = MFMAs(af, bf, acc[t]);
    }
  }
#pragma unroll
  for (int t = 0; t < 4; ++t) {
    int mbase = (wave + t * 4) * 16 + lg * 4;
#pragma unroll
    for (int r = 0; r < 4; ++r)
      P.x[(size_t)(1 + mbase + r) * E_DIM + n0 + lc] = fmaxf(acc[t][r], 0.f);
  }
}

// ---------------------------------------------------------------------------
// residual-reduce + LayerNorm for one token row m
// ---------------------------------------------------------------------------
__device__ void phase_ln(float* x, const float* part, int nparts, const float* rbias,
                         const float* lns, const float* lnb, unsigned short* hout,
                         int m, int tid, char* smem) {
  float* red = (float*)smem;
  int c0 = tid * 4;
  float4_t v = *(const float4_t*)(x + (size_t)m * E_DIM + c0);
  if (rbias) v += *(const float4_t*)(rbias + c0);
  for (int s = 0; s < nparts; ++s)
    v += *(const float4_t*)(part + ((size_t)s * MPAD + m) * E_DIM + c0);
  if (nparts > 0) *(float4_t*)(x + (size_t)m * E_DIM + c0) = v;
  float s1 = v[0] + v[1] + v[2] + v[3];
  float s2 = v[0] * v[0] + v[1] * v[1] + v[2] * v[2] + v[3] * v[3];
#pragma unroll
  for (int off = 1; off < 64; off <<= 1) {
    s1 += __shfl_xor(s1, off, 64);
    s2 += __shfl_xor(s2, off, 64);
  }
  int wave = tid >> 6, lane = tid & 63;
  if (lane == 0) { red[wave * 2] = s1; red[wave * 2 + 1] = s2; }
  __syncthreads();
  s1 = red[0] + red[2] + red[4] + red[6];
  s2 = red[1] + red[3] + red[5] + red[7];
  float mean = s1 * (1.f / 1024.f);
  float var = s2 * (1.f / 1024.f) - mean * mean;
  float rstd = rsqrtf(var + 1e-5f);
  float4_t ls = *(const float4_t*)(lns + c0);
  float4_t lb = *(const float4_t*)(lnb + c0);
  ushort4_t hv;
#pragma unroll
  for (int r = 0; r < 4; ++r) hv[r] = f2bf((v[r] - mean) * rstd * ls[r] + lb[r]);
  *(ushort4_t*)(hout + (size_t)m * E_DIM + c0) = hv;
  __syncthreads();
}

// ---------------------------------------------------------------------------
// GEMM phase (R7 structure): per K-tile of 128: [hoist A-tile to regs first]
// -> [async glds W tile t+1] -> [compute from LDS] -> [__syncthreads drain].
// ---------------------------------------------------------------------------
template <int NTOT, int EPI, int NK>
__device__ void phase_gemm(char* smem, int item, int NT,
                           const unsigned short* __restrict__ A, int lda,
                           const float* __restrict__ Wa, const float* __restrict__ Wb2,
                           const float* __restrict__ Wc,
                           const float* __restrict__ ba, const float* __restrict__ bb,
                           const float* __restrict__ bc,
                           unsigned short* __restrict__ oq, unsigned short* __restrict__ okk,
                           unsigned short* __restrict__ ovT, unsigned short* __restrict__ om,
                           float* __restrict__ opart, int tid) {
  float* Wt = (float*)smem;   // [2][128][16] f32
  int nt = item % NT, ks = item / NT;
  int wave = tid >> 6, lane = tid & 63;
  int lg = lane >> 4, lc = lane & 15;

  const float* W; const float* bias; int ncol;
  if (EPI == 0) {
    int sel = nt >> 6; ncol = (nt & 63) << 4;
    W = (sel == 0) ? Wa : ((sel == 1) ? Wb2 : Wc);
    bias = (sel == 0) ? ba : ((sel == 1) ? bb : bc);
  } else {
    ncol = nt << 4; W = Wa; bias = ba;
  }

  const int kb0 = ks * (NK * 128);
  const float* wsrc0 = W + (size_t)(kb0 + (lane >> 2)) * NTOT + ncol + (lane & 3) * 4;

  const unsigned short* ap[5];
#pragma unroll
  for (int j = 0; j < 5; ++j)
    ap[j] = A + (size_t)((wave + 4 * j) * 16 + lc) * lda + kb0 + lg * 8;

  float4_t acc[5] = {{0,0,0,0},{0,0,0,0},{0,0,0,0},{0,0,0,0},{0,0,0,0}};

  // prologue: stage tile 0 into buf 0
#pragma unroll
  for (int i = 0; i < 2; ++i) {
    int rg = wave * 32 + i * 16;
    int off = __builtin_amdgcn_readfirstlane(rg * 16);
    glds16(wsrc0 + (size_t)rg * NTOT, Wt + off);
  }
  __syncthreads();

  for (int t = 0; t < NK; ++t) {
    // 1) hoist full A-tile to registers (oldest vmcnt entries)
    short8 av[20];
#pragma unroll
    for (int s = 0; s < 4; ++s)
#pragma unroll
      for (int j = 0; j < 5; ++j)
        av[s * 5 + j] = *(const short8*)(ap[j] + s * 32);
#pragma unroll
    for (int j = 0; j < 5; ++j) ap[j] += 128;

    // 2) async stage of W tile t+1
    if (t + 1 < NK) {
      const float* sn = wsrc0 + (size_t)(t + 1) * 128 * NTOT;
      float* bufn = Wt + ((t + 1) & 1) * 2048;
#pragma unroll
      for (int i = 0; i < 2; ++i) {
        int rg = wave * 32 + i * 16;
        int off = __builtin_amdgcn_readfirstlane(rg * 16);
        glds16(sn + (size_t)rg * NTOT, bufn + off);
      }
    }

    // 3) compute tile t from LDS
    const float* Wb_ = Wt + (t & 1) * 2048;
#pragma unroll
    for (int s = 0; s < 4; ++s) {
      float wv[8];
#pragma unroll
      for (int i = 0; i < 8; ++i) wv[i] = Wb_[(s * 32 + lg * 8 + i) * 16 + lc];
      bf16x8 wf;
#pragma unroll
      for (int i = 0; i < 8; ++i) wf[i] = (__bf16)wv[i];
#pragma unroll
      for (int j = 0; j < 5; ++j) {
        ABu a; a.s = av[s * 5 + j];
        acc[j] = MFMA(wf, a.b, acc[j]);
      }
    }
    __syncthreads();   // single drain per tile
  }

  float4_t bvv = {0,0,0,0};
  if (bias) bvv = *(const float4_t*)(bias + ncol + lg * 4);

  if (EPI == 0) {
    int sel = nt >> 6;
    int head = ncol >> 6;
    int dbase = (ncol & 63) + lg * 4;
#pragma unroll
    for (int j = 0; j < 5; ++j) {
      int tile = wave + 4 * j;
      int m = tile * 16 + lc;
      if (sel < 2) {
        unsigned short* dst = (sel == 0 ? oq : okk) + ((size_t)(head * MPAD + m)) * 64 + dbase;
        ushort4_t hv;
#pragma unroll
        for (int r = 0; r < 4; ++r) hv[r] = f2bf(acc[j][r] + bvv[r]);
        *(ushort4_t*)dst = hv;
      } else if (tile < 17) {
#pragma unroll
        for (int r = 0; r < 4; ++r)
          ovT[(size_t)(head * 64 + dbase + r) * SPAD + m] = f2bf(acc[j][r] + bvv[r]);
      }
    }
  } else if (EPI == 1) {
#pragma unroll
    for (int j = 0; j < 5; ++j) {
      int m = (wave + 4 * j) * 16 + lc;
      ushort4_t hv;
#pragma unroll
      for (int r = 0; r < 4; ++r) {
        float v = acc[j][r] + bvv[r];
        v = v / (1.f + __expf(-1.702f * v));
        hv[r] = f2bf(v);
      }
      *(ushort4_t*)(om + (size_t)m * FF_DIM + ncol + lg * 4) = hv;
    }
  } else {
#pragma unroll
    for (int j = 0; j < 5; ++j) {
      int m = (wave + 4 * j) * 16 + lc;
      *(float4_t*)(opart + ((size_t)ks * MPAD + m) * E_DIM + ncol + lg * 4) = acc[j];
    }
  }
}

// ---------------------------------------------------------------------------
// Attention: item v = head*17 + qtile
// ---------------------------------------------------------------------------
__device__ void phase_attn(const MegaParams& P, char* smem, int v, int tid) {
  float* smax = (float*)smem;
  float* sden = smax + 64;
  unsigned short* Pl = (unsigned short*)(sden + 64);  // [16][288]
  int head = v / 17, qt = v % 17;
  int q0 = qt * 16;
  int wave = tid >> 6, lane = tid & 63;
  int lg = lane >> 4, lc = lane & 15;
  const unsigned short* qh = P.qb + (size_t)head * MPAD * 64;
  const unsigned short* kh = P.kb + (size_t)head * MPAD * 64;
  const unsigned short* vh = P.vT + (size_t)head * 64 * SPAD;

  short8 aq0 = *(const short8*)(qh + (size_t)(q0 + lc) * 64 + lg * 8);
  short8 aq1 = *(const short8*)(qh + (size_t)(q0 + lc) * 64 + 32 + lg * 8);

  float4_t sc[5];
  int st[5]; int nst = 0;
#pragma unroll
  for (int j = 0; j < 5; ++j) {
    int t = wave + j * 4;
    st[j] = (t < 17) ? t : 0;
    if (t < 17) nst = j + 1;
    sc[j] = (float4_t){0,0,0,0};
  }
#pragma unroll
  for (int j = 0; j < 5; ++j) {
    if (j < nst) {
      const unsigned short* kp = kh + (size_t)(st[j] * 16 + lc) * 64 + lg * 8;
      short8 b0 = *(const short8*)kp;
      short8 b1 = *(const short8*)(kp + 32);
      sc[j] = MFMAs(aq0, b0, sc[j]);
      sc[j] = MFMAs(aq1, b1, sc[j]);
    }
  }
  float mx[4] = {-1e30f, -1e30f, -1e30f, -1e30f};
#pragma unroll
  for (int j = 0; j < 5; ++j) {
    if (j < nst) {
      int sg = st[j] * 16 + lc;
#pragma unroll
      for (int r = 0; r < 4; ++r) {
        float vv = sc[j][r] * 0.125f;
        if (sg >= 257) vv = -1e30f;
        else if (q0 + lg * 4 + r == 0 && sg >= 1) vv += P.pbv[sg - 1];
        sc[j][r] = vv;
        mx[r] = fmaxf(mx[r], vv);
      }
    }
  }
#pragma unroll
  for (int r = 0; r < 4; ++r) {
    mx[r] = fmaxf(mx[r], __shfl_xor(mx[r], 1, 64));
    mx[r] = fmaxf(mx[r], __shfl_xor(mx[r], 2, 64));
    mx[r] = fmaxf(mx[r], __shfl_xor(mx[r], 4, 64));
    mx[r] = fmaxf(mx[r], __shfl_xor(mx[r], 8, 64));
  }
  if (lc == 0) {
#pragma unroll
    for (int r = 0; r < 4; ++r) smax[wave * 16 + lg * 4 + r] = mx[r];
  }
  __syncthreads();
  float fm[4], den[4] = {0, 0, 0, 0};
#pragma unroll
  for (int r = 0; r < 4; ++r) {
    int qq = lg * 4 + r;
    fm[r] = fmaxf(fmaxf(smax[qq], smax[16 + qq]), fmaxf(smax[32 + qq], smax[48 + qq]));
  }
#pragma unroll
  for (int j = 0; j < 5; ++j) {
    if (j < nst) {
#pragma unroll
      for (int r = 0; r < 4; ++r) {
        float pe = __expf(sc[j][r] - fm[r]);
        sc[j][r] = pe;
        den[r] += pe;
      }
    }
  }
#pragma unroll
  for (int r = 0; r < 4; ++r) {
    den[r] += __shfl_xor(den[r], 1, 64);
    den[r] += __shfl_xor(den[r], 2, 64);
    den[r] += __shfl_xor(den[r], 4, 64);
    den[r] += __shfl_xor(den[r], 8, 64);
  }
  if (lc == 0) {
#pragma unroll
    for (int r = 0; r < 4; ++r) sden[wave * 16 + lg * 4 + r] = den[r];
  }
  Pl[(tid >> 4) * SPAD + 272 + (tid & 15)] = 0;
#pragma unroll
  for (int j = 0; j < 5; ++j) {
    if (j < nst) {
#pragma unroll
      for (int r = 0; r < 4; ++r) Pl[(lg * 4 + r) * SPAD + st[j] * 16 + lc] = f2bf(sc[j][r]);
    }
  }
  __syncthreads();
  float denf[4];
#pragma unroll
  for (int r = 0; r < 4; ++r) {
    int qq = lg * 4 + r;
    denf[r] = sden[qq] + sden[16 + qq] + sden[32 + qq] + sden[48 + qq];
  }
  int d0 = wave * 16;
  float4_t oa = {0, 0, 0, 0};
#pragma unroll
  for (int s9 = 0; s9 < 9; ++s9) {
    short8 pa = *(const short8*)(Pl + lc * SPAD + s9 * 32 + lg * 8);
    short8 bv = *(const short8*)(vh + (size_t)(d0 + lc) * SPAD + s9 * 32 + lg * 8);
    oa = MFMAs(pa, bv, oa);
  }
#pragma unroll
  for (int r = 0; r < 4; ++r) {
    int qg = q0 + lg * 4 + r;
    P.ob[(size_t)qg * E_DIM + head * 64 + d0 + lc] = f2bf(oa[r] / denf[r]);
  }
  __syncthreads();   // safe smem reuse for a 2nd item
}

// ---------------------------------------------------------------------------
// ROI phase
// ---------------------------------------------------------------------------
__device__ void phase_roi(const MegaParams& P, char* smem, int v, int tid) {
  int c0 = tid * 4;
  if (v == 0) {
    *(float4_t*)(P.out + c0) = *(const float4_t*)(P.x + c0);
  } else {
    float* mi = (float*)smem;
    mi[tid] = P.Mi[(v - 1) * 256 + tid];
    __syncthreads();
    float4_t acc = {0, 0, 0, 0};
    for (int p = 0; p < 256; ++p) {
      float4_t xv = *(const float4_t*)(P.x + (size_t)(1 + p) * E_DIM + c0);
      acc += mi[p] * xv;
    }
    *(float4_t*)(P.out + (size_t)v * E_DIM + c0) = acc;
  }
}

// ---------------------------------------------------------------------------
// Persistent megakernel v2
// ---------------------------------------------------------------------------
__global__ __launch_bounds__(256) void vit_mega(MegaParams P) {
  __shared__ __align__(16) char smem[16384];
  const int bid = blockIdx.x, tid = threadIdx.x;
  unsigned* bar = P.bar;
  unsigned gen = 0;
  // XCD-paired item decode for gemm phases (items 2p,2p+1 on same XCD)
  const int gitem = (((bid & 7) | ((bid >> 4) << 3)) << 1) | ((bid >> 3) & 1);

  phase_prep(P, bid * 256 + tid);
  gsync(bar, bid, ++gen);

  if (bid == NB - 1) phase_pbcls(P, smem, tid);
  else if (bid < 64) phase_conv(P, bid, tid);
  gsync(bar, bid, ++gen);

  for (int m = bid; m < 257; m += NB)
    phase_ln(P.x, nullptr, 0, nullptr, P.ln1_s, P.ln1_b, P.h, m, tid, smem);
  gsync(bar, bid, ++gen);

  for (int l = 0; l < LAYERS; ++l) {
    const size_t o2 = (size_t)l * E_DIM * E_DIM;
    const size_t o1 = (size_t)l * E_DIM;
    const size_t of1 = (size_t)l * E_DIM * FF_DIM;
    const size_t ofb = (size_t)l * FF_DIM;

    // QKV: 192 items (nt -> q/k/vT), K=1024 = 8 tiles
    if (gitem < 192)
      phase_gemm<1024, 0, 8>(smem, gitem, 192, P.h, E_DIM,
                             P.wq + o2, P.wk + o2, P.wv + o2,
                             P.bq + o1, P.bk + o1, P.bv + o1,
                             P.qb, P.kb, P.vT, nullptr, nullptr, tid);
    gsync(bar, bid, ++gen);

    for (int v = bid; v < 272; v += NB) phase_attn(P, smem, v, tid);
    gsync(bar, bid, ++gen);

    // O-proj: 256 items = 64 nt x KS4 (chunk 256 = 2 tiles) -> partials
    phase_gemm<1024, 2, 2>(smem, gitem, 64, P.ob, E_DIM,
                           P.wo + o2, nullptr, nullptr, nullptr, nullptr, nullptr,
                           nullptr, nullptr, nullptr, nullptr, P.part, tid);
    gsync(bar, bid, ++gen);

    for (int m = bid; m < 257; m += NB)
      phase_ln(P.x, P.part, 4, P.bo + o1, P.ln2_s + o1, P.ln2_b + o1, P.h, m, tid, smem);
    gsync(bar, bid, ++gen);

    // FF1: 256 items, K=1024 = 8 tiles; fused bias+quickgelu
    phase_gemm<4096, 1, 8>(smem, gitem, 256, P.h, E_DIM,
                           P.w1 + of1, nullptr, nullptr, P.b1 + ofb, nullptr, nullptr,
                           nullptr, nullptr, nullptr, P.mb, nullptr, tid);
    gsync(bar, bid, ++gen);

    // FF2: 256 items = 64 nt x KS4 (chunk 1024 = 8 tiles) -> partials
    phase_gemm<1024, 2, 8>(smem, gitem, 64, P.mb, FF_DIM,
                           P.w2 + of1, nullptr, nullptr, nullptr, nullptr, nullptr,
                           nullptr, nullptr, nullptr, nullptr, P.part, tid);
    gsync(bar, bid, ++gen);

    const float* nls = (l < LAYERS - 1) ? (P.ln1_s + (size_t)(l + 1) * E_DIM) : P.ln1_s;
    const float* nlb = (l < LAYERS - 1) ? (P.ln1_b + (size_t)(l + 1) * E_DIM) : P.ln1_b;
    for (int m = bid; m < 257; m += NB)
      phase_ln(P.x, P.part, 4, P.b2 + o1, nls, nlb, P.h, m, tid, smem);
    gsync(bar, bid, ++gen);
  }

  for (int v = bid; v < 33; v += NB) phase_roi(P, smem, v, tid);
}

// ---------------------------------------------------------------------------
extern "C" void kernel_launch(void* const* d_in, const int* in_sizes, int n_in,
                              void* d_out, int out_size, void* d_ws, size_t ws_size,
                              hipStream_t stream) {
  char* base = (char*)d_ws;
  auto carve = [&](size_t bytes) {
    char* r = base;
    base += (bytes + 255) & ~(size_t)255;
    return r;
  };
  unsigned* bar       = (unsigned*)carve(36864);   // slots (32KB) + broadcast
  float* x            = (float*)carve((size_t)257 * E_DIM * 4);
  unsigned short* h   = (unsigned short*)carve((size_t)MPAD * E_DIM * 2);
  unsigned short* qb  = (unsigned short*)carve((size_t)16 * MPAD * 64 * 2);
  unsigned short* kbf = (unsigned short*)carve((size_t)16 * MPAD * 64 * 2);
  unsigned short* vTb = (unsigned short*)carve((size_t)16 * 64 * SPAD * 2);
  unsigned short* ob  = (unsigned short*)carve((size_t)MPAD * E_DIM * 2);
  unsigned short* mb  = (unsigned short*)carve((size_t)MPAD * FF_DIM * 2);
  float* part         = (float*)carve((size_t)4 * MPAD * E_DIM * 4);
  float* pbv          = (float*)carve(256 * 4);
  float* Mi           = (float*)carve(32 * 256 * 4);
  unsigned short* Pm  = (unsigned short*)carve((size_t)256 * KCP * 2);
  unsigned short* Wp  = (unsigned short*)carve((size_t)1024 * KCP * 2);

  MegaParams mp;
  mp.frame  = (const float*)d_in[0];
  mp.bboxes = (const float*)d_in[1];
  mp.conv_w = (const float*)d_in[2];
  mp.cls_emb= (const float*)d_in[3];
  mp.ln1_s  = (const float*)d_in[4];
  mp.ln1_b  = (const float*)d_in[5];
  mp.wq = (const float*)d_in[6];  mp.bq = (const float*)d_in[7];
  mp.wk = (const float*)d_in[8];  mp.bk = (const float*)d_in[9];
  mp.wv = (const float*)d_in[10]; mp.bv = (const float*)d_in[11];
  mp.wo = (const float*)d_in[12]; mp.bo = (const float*)d_in[13];
  mp.ln2_s = (const float*)d_in[14]; mp.ln2_b = (const float*)d_in[15];
  mp.w1 = (const float*)d_in[16]; mp.b1 = (const float*)d_in[17];
  mp.w2 = (const float*)d_in[18]; mp.b2 = (const float*)d_in[19];
  mp.x = x; mp.h = h; mp.qb = qb; mp.kb = kbf; mp.vT = vTb; mp.ob = ob; mp.mb = mb;
  mp.part = part; mp.pbv = pbv; mp.Mi = Mi; mp.Pm = Pm; mp.Wp = Wp;
  mp.out = (float*)d_out; mp.bar = bar;

  hipMemsetAsync(bar, 0, 36864, stream);
  vit_mega<<<NB, 256, 0, stream>>>(mp);
}

// Round 9
// 2042.404 us; speedup vs baseline: 5.5720x; 5.5720x over previous
//
#include <hip/hip_runtime.h>
#include <hip/hip_bf16.h>
#include <math.h>

#define E_DIM 1024
#define FF_DIM 4096
#define LAYERS 24
#define MPAD 384      // 24 * 16 token-row padding (rows 257..383 zero / ignored)
#define SPAD 288      // vT / P column padding (9 * 32)
#define KCP 608       // conv K (588) padded to 19*32

typedef __attribute__((ext_vector_type(8))) short short8;
typedef __attribute__((ext_vector_type(8))) __bf16 bf16x8;
typedef __attribute__((ext_vector_type(4))) float float4_t;
typedef __attribute__((ext_vector_type(4))) unsigned short ushort4_t;

union ABu { short8 s; bf16x8 b; };
union BFU { __bf16 b; unsigned short u; };

__device__ __forceinline__ float4_t MFMA(bf16x8 a, bf16x8 b, float4_t c) {
  return __builtin_amdgcn_mfma_f32_16x16x32_bf16(a, b, c, 0, 0, 0);
}
__device__ __forceinline__ float4_t MFMAs(short8 a, short8 b, float4_t c) {
  ABu ua, ub; ua.s = a; ub.s = b;
  return __builtin_amdgcn_mfma_f32_16x16x32_bf16(ua.b, ub.b, c, 0, 0, 0);
}
__device__ __forceinline__ unsigned short f2bf(float f) {
  BFU x; x.b = (__bf16)f; return x.u;
}

// async global->LDS: 16B per lane, LDS dest = wave-uniform base + lane*16
__device__ __forceinline__ void glds16(const float* src, float* dst) {
  __builtin_amdgcn_global_load_lds(
      (const __attribute__((address_space(1))) unsigned int*)src,
      (__attribute__((address_space(3))) unsigned int*)dst, 16, 0, 0);
}

// ---------------------------------------------------------------------------
// prep: im2col frame -> Pm ; conv_w -> Wp ; zero pads of h / ob / vT
// ---------------------------------------------------------------------------
__global__ void prep_kernel(const float* __restrict__ frame, const float* __restrict__ conv_w,
                            unsigned short* __restrict__ Pm, unsigned short* __restrict__ Wp,
                            unsigned short* __restrict__ h, unsigned short* __restrict__ ob,
                            unsigned short* __restrict__ vTb) {
  int b = blockIdx.x, tid = threadIdx.x;
  if (b < 256) {
    int pr = b >> 4, pc = b & 15;
    for (int kk = tid; kk < KCP; kk += 256) {
      unsigned short us = 0;
      if (kk < 588) {
        int c = kk / 196, rem = kk % 196;
        int i = rem / 14, j = rem % 14;
        us = f2bf(frame[c * 224 * 224 + (pr * 14 + i) * 224 + (pc * 14 + j)]);
      }
      Pm[b * KCP + kk] = us;
    }
  } else if (b < 1280) {
    int n = b - 256;
    for (int kk = tid; kk < KCP; kk += 256) {
      unsigned short us = (kk < 588) ? f2bf(conv_w[n * 588 + kk]) : (unsigned short)0;
      Wp[n * KCP + kk] = us;
    }
  } else {
    int idx = (b - 1280) * 256 + tid;
    const int NH = (MPAD - 257) * E_DIM;   // 130048
    const int NO = (MPAD - 272) * E_DIM;   // 114688
    const int NV = 16 * 64 * (SPAD - 272); // 16384
    if (idx < NH) {
      h[257 * E_DIM + idx] = 0;
    } else if (idx < NH + NO) {
      ob[272 * E_DIM + (idx - NH)] = 0;
    } else if (idx < NH + NO + NV) {
      int i = idx - NH - NO;
      vTb[(size_t)(i >> 4) * SPAD + 272 + (i & 15)] = 0;
    }
  }
}

// ---------------------------------------------------------------------------
// pb_cls
// ---------------------------------------------------------------------------
__global__ void pb_cls_kernel(const float* __restrict__ bboxes, const float* __restrict__ cls_emb,
                              float* __restrict__ pb, float* __restrict__ Mi, float* __restrict__ x) {
  __shared__ float sb[128];
  __shared__ float red[256];
  int tid = threadIdx.x;
  if (tid < 128) sb[tid] = bboxes[tid];
  __syncthreads();
  int p = tid;
  float px1 = (float)((p & 15) * 14), py1 = (float)((p >> 4) * 14);
  float px2 = px1 + 14.f, py2 = py1 + 14.f;
  float s = 0.f;
  for (int r = 0; r < 32; ++r) {
    float bx1 = sb[r * 4 + 0], by1 = sb[r * 4 + 1], bx2 = sb[r * 4 + 2], by2 = sb[r * 4 + 3];
    float iw = fmaxf(fminf(bx2, px2) - fmaxf(bx1, px1), 0.f);
    float ih = fmaxf(fminf(by2, py2) - fmaxf(by1, py1), 0.f);
    float ov = iw * ih * (1.f / 196.f);
    Mi[r * 256 + p] = ov;
    s += ov;
  }
  red[tid] = s;
  __syncthreads();
  for (int off = 128; off > 0; off >>= 1) {
    if (tid < off) red[tid] = fmaxf(red[tid], red[tid + off]);
    __syncthreads();
  }
  pb[p] = s / (red[0] + 1e-6f);
  for (int j = 0; j < 4; ++j) x[tid * 4 + j] = cls_emb[tid * 4 + j];
}

// ---------------------------------------------------------------------------
// conv GEMM
// ---------------------------------------------------------------------------
__global__ __launch_bounds__(256) void conv_gemm(const unsigned short* __restrict__ Pm,
                                                 const unsigned short* __restrict__ Wp,
                                                 float* __restrict__ x) {
  int n0 = blockIdx.x * 16;
  int tid = threadIdx.x, wave = tid >> 6, lane = tid & 63;
  int lg = lane >> 4, lc = lane & 15;
  float4_t acc[4] = {{0,0,0,0},{0,0,0,0},{0,0,0,0},{0,0,0,0}};
  const unsigned short* bp = Wp + (size_t)(n0 + lc) * KCP + lg * 8;
  const unsigned short* apt[4];
#pragma unroll
  for (int t = 0; t < 4; ++t) apt[t] = Pm + (size_t)((wave + t * 4) * 16 + lc) * KCP + lg * 8;
  for (int s = 0; s < 19; ++s) {
    short8 bf = *(const short8*)bp; bp += 32;
#pragma unroll
    for (int t = 0; t < 4; ++t) {
      short8 af = *(const short8*)apt[t]; apt[t] += 32;
      acc[t] = MFMAs(af, bf, acc[t]);
    }
  }
#pragma unroll
  for (int t = 0; t < 4; ++t) {
    int mbase = (wave + t * 4) * 16 + lg * 4;
#pragma unroll
    for (int r = 0; r < 4; ++r)
      x[(size_t)(1 + mbase + r) * E_DIM + n0 + lc] = fmaxf(acc[t][r], 0.f);
  }
}

// ---------------------------------------------------------------------------
// GEMM: C[m][n] = A[m][:] (bf16) . W[:][n] (fp32->bf16)
// Block = 32 N-cols x 192 M-rows (M-half, 3 m-tiles/wave) x K-chunk (NK x 128).
// Counted-vmcnt pipeline (never drain to 0 in loop): 3 LDS W-buffers, glds
// prefetch depth 2, A double-buffered in regs (issued oldest each iter).
// Per iter t: [issue A(t+1)] [issue glds(t+2)] [compute t] [vmcnt(4); s_barrier]
//   -> the wait retires glds(t+1) (issued a full iter ago) + A(t+1), leaving
//      only glds(t+2) in flight. Latency hidden, no full drain.
// LDS col-XOR swizzle key=8*((row>>3)&3) applied on the glds SOURCE address;
// ds_reads then hit 2 banks-halves (2-way = free) instead of 4-way.
// XCD pairing: blocks b, b+8 (same XCD) are the two M-halves of one N-slice.
// EPI 0: q/k/vT scatter (+bias)  EPI 1: quickgelu (+bias)  EPI 2: fp32 partial
// ---------------------------------------------------------------------------
template <int NTOT, int EPI, int NK>
__global__ __launch_bounds__(256, 1) void gemm_nk(
    const unsigned short* __restrict__ A, int lda,
    const float* __restrict__ Wa, const float* __restrict__ Wb2, const float* __restrict__ Wc,
    const float* __restrict__ ba, const float* __restrict__ bb, const float* __restrict__ bc,
    int NNT,
    unsigned short* __restrict__ oq, unsigned short* __restrict__ okk,
    unsigned short* __restrict__ ovT, unsigned short* __restrict__ om,
    float* __restrict__ opart) {
  static_assert(NK >= 2, "pipeline needs >=2 K-tiles");
  __shared__ __align__(16) float Wt[3][128][32];
  int b = blockIdx.x;
  int p = ((b >> 4) << 3) | (b & 7);   // pair id: b and b+8 share slice & XCD
  int mh = (b >> 3) & 1;
  int nt = p % NNT, ks = p / NNT;

  int tid = threadIdx.x, wave = tid >> 6, lane = tid & 63;
  int lg = lane >> 4, lc = lane & 15;

  const float* W; const float* bias; int ncl;
  if (EPI == 0) {
    int sel = nt >> 5; ncl = (nt & 31) << 5;
    W = (sel == 0) ? Wa : ((sel == 1) ? Wb2 : Wc);
    bias = (sel == 0) ? ba : ((sel == 1) ? bb : bc);
  } else {
    ncl = nt << 5; W = Wa; bias = ba;
  }

  const int kb0 = ks * (NK * 128);

  // staging: 4 glds/wave/tile; op covers rows [wave*32+op*8,+8), lane: row
  // +(lane>>3), cols 4*(lane&7) (16B), col-XOR swizzled on the global source
  const float* wsrc[4];
  int dsto[4];
#pragma unroll
  for (int op = 0; op < 4; ++op) {
    int rbase = wave * 32 + op * 8;
    int row = rbase + (lane >> 3);
    int key = 8 * ((wave * 4 + op) & 3);
    int col = ((lane & 7) * 4) ^ key;
    wsrc[op] = W + (size_t)(kb0 + row) * NTOT + ncl + col;
    dsto[op] = __builtin_amdgcn_readfirstlane(rbase * 32);
  }

  const unsigned short* ap[3];
#pragma unroll
  for (int j = 0; j < 3; ++j) {
    int t0 = mh * 12 + wave * 3 + j;
    ap[j] = A + (size_t)(t0 * 16 + lc) * lda + kb0 + lg * 8;
  }

  float4_t acc[6];   // [mtile j][frag f] -> acc[j*2+f]
#pragma unroll
  for (int i = 0; i < 6; ++i) acc[i] = (float4_t){0, 0, 0, 0};

  short8 av[2][12];
  // A(0) — issued first (oldest vmcnt entries)
#pragma unroll
  for (int s = 0; s < 4; ++s)
#pragma unroll
    for (int j = 0; j < 3; ++j)
      av[0][s * 3 + j] = *(const short8*)(ap[j] + s * 32);
#pragma unroll
  for (int j = 0; j < 3; ++j) ap[j] += 128;

  // glds tiles 0, 1
#pragma unroll
  for (int op = 0; op < 4; ++op) glds16(wsrc[op], &Wt[0][0][0] + dsto[op]);
#pragma unroll
  for (int op = 0; op < 4; ++op)
    glds16(wsrc[op] + (size_t)128 * NTOT, &Wt[1][0][0] + dsto[op]);
  // retire A(0)+glds(0); keep glds(1) in flight
  asm volatile("s_waitcnt vmcnt(4)\n\ts_barrier" ::: "memory");

  // read bases: addr = s*1024 + lg*256 + ((f*16+lc) ^ (8*lg)) + d*32
  const int cx0 = lg * 256 + (lc ^ (8 * lg));
  const int cx1 = lg * 256 + ((16 + lc) ^ (8 * lg));

#pragma unroll
  for (int t = 0; t < NK; ++t) {
    if (t + 1 < NK) {
#pragma unroll
      for (int s = 0; s < 4; ++s)
#pragma unroll
        for (int j = 0; j < 3; ++j)
          av[(t + 1) & 1][s * 3 + j] = *(const short8*)(ap[j] + s * 32);
#pragma unroll
      for (int j = 0; j < 3; ++j) ap[j] += 128;
    }
    if (t + 2 < NK) {
      float* bufn = &Wt[(t + 2) % 3][0][0];
#pragma unroll
      for (int op = 0; op < 4; ++op)
        glds16(wsrc[op] + (size_t)(t + 2) * 128 * NTOT, bufn + dsto[op]);
    }
    const float* Wb_ = &Wt[t % 3][0][0];
#pragma unroll
    for (int s = 0; s < 4; ++s) {
      bf16x8 wf0, wf1;
#pragma unroll
      for (int d = 0; d < 8; ++d) {
        wf0[d] = (__bf16)Wb_[s * 1024 + cx0 + d * 32];
        wf1[d] = (__bf16)Wb_[s * 1024 + cx1 + d * 32];
      }
#pragma unroll
      for (int j = 0; j < 3; ++j) {
        ABu a; a.s = av[t & 1][s * 3 + j];
        acc[j * 2 + 0] = MFMA(wf0, a.b, acc[j * 2 + 0]);
        acc[j * 2 + 1] = MFMA(wf1, a.b, acc[j * 2 + 1]);
      }
    }
    if (t + 1 < NK) {
      if (t + 2 < NK) asm volatile("s_waitcnt vmcnt(4)\n\ts_barrier" ::: "memory");
      else            asm volatile("s_waitcnt vmcnt(0)\n\ts_barrier" ::: "memory");
    }
  }

  float4_t bv0 = {0,0,0,0}, bv1 = {0,0,0,0};
  if (bias) {
    bv0 = *(const float4_t*)(bias + ncl + lg * 4);
    bv1 = *(const float4_t*)(bias + ncl + 16 + lg * 4);
  }

  if (EPI == 0) {
    int sel = nt >> 5;
    int head = ncl >> 6;
    int db0 = (ncl & 63) + lg * 4;
    int db1 = (ncl & 63) + 16 + lg * 4;
#pragma unroll
    for (int j = 0; j < 3; ++j) {
      int tile = mh * 12 + wave * 3 + j;
      int m = tile * 16 + lc;
      if (sel < 2) {
        unsigned short* dst = (sel == 0 ? oq : okk) + ((size_t)(head * MPAD + m)) * 64;
        ushort4_t h0, h1;
#pragma unroll
        for (int r = 0; r < 4; ++r) {
          h0[r] = f2bf(acc[j * 2 + 0][r] + bv0[r]);
          h1[r] = f2bf(acc[j * 2 + 1][r] + bv1[r]);
        }
        *(ushort4_t*)(dst + db0) = h0;
        *(ushort4_t*)(dst + db1) = h1;
      } else if (tile < 17) {   // vT columns only exist for m < 272
#pragma unroll
        for (int r = 0; r < 4; ++r) {
          ovT[(size_t)(head * 64 + db0 + r) * SPAD + m] = f2bf(acc[j * 2 + 0][r] + bv0[r]);
          ovT[(size_t)(head * 64 + db1 + r) * SPAD + m] = f2bf(acc[j * 2 + 1][r] + bv1[r]);
        }
      }
    }
  } else if (EPI == 1) {
#pragma unroll
    for (int j = 0; j < 3; ++j) {
      int m = (mh * 12 + wave * 3 + j) * 16 + lc;
      ushort4_t h0, h1;
#pragma unroll
      for (int r = 0; r < 4; ++r) {
        float v0 = acc[j * 2 + 0][r] + bv0[r];
        float v1 = acc[j * 2 + 1][r] + bv1[r];
        h0[r] = f2bf(v0 / (1.f + __expf(-1.702f * v0)));
        h1[r] = f2bf(v1 / (1.f + __expf(-1.702f * v1)));
      }
      *(ushort4_t*)(om + (size_t)m * FF_DIM + ncl + lg * 4) = h0;
      *(ushort4_t*)(om + (size_t)m * FF_DIM + ncl + 16 + lg * 4) = h1;
    }
  } else {
#pragma unroll
    for (int j = 0; j < 3; ++j) {
      int m = (mh * 12 + wave * 3 + j) * 16 + lc;
      float* dst = opart + ((size_t)ks * MPAD + m) * E_DIM + ncl + lg * 4;
      *(float4_t*)dst = acc[j * 2 + 0];
      *(float4_t*)(dst + 16) = acc[j * 2 + 1];
    }
  }
}

// ---------------------------------------------------------------------------
// Attention: grid = 16 heads * 17 q-tiles
// ---------------------------------------------------------------------------
__global__ __launch_bounds__(256) void attn_kernel(
    const unsigned short* __restrict__ qb, const unsigned short* __restrict__ kb,
    const unsigned short* __restrict__ vT, const float* __restrict__ pb,
    unsigned short* __restrict__ ob) {
  int head = blockIdx.x / 17, qt = blockIdx.x % 17;
  int q0 = qt * 16;
  int tid = threadIdx.x, wave = tid >> 6, lane = tid & 63;
  int lg = lane >> 4, lc = lane & 15;
  const unsigned short* qh = qb + (size_t)head * MPAD * 64;
  const unsigned short* kh = kb + (size_t)head * MPAD * 64;
  const unsigned short* vh = vT + (size_t)head * 64 * SPAD;

  short8 aq0 = *(const short8*)(qh + (size_t)(q0 + lc) * 64 + lg * 8);
  short8 aq1 = *(const short8*)(qh + (size_t)(q0 + lc) * 64 + 32 + lg * 8);

  float4_t sc[5];
  int st[5]; int nst = 0;
#pragma unroll
  for (int j = 0; j < 5; ++j) {
    int t = wave + j * 4;
    st[j] = (t < 17) ? t : 0;
    if (t < 17) nst = j + 1;
    sc[j] = (float4_t){0,0,0,0};
  }
#pragma unroll
  for (int j = 0; j < 5; ++j) {
    if (j < nst) {
      const unsigned short* kp = kh + (size_t)(st[j] * 16 + lc) * 64 + lg * 8;
      short8 b0 = *(const short8*)kp;
      short8 b1 = *(const short8*)(kp + 32);
      sc[j] = MFMAs(aq0, b0, sc[j]);
      sc[j] = MFMAs(aq1, b1, sc[j]);
    }
  }
  float mx[4] = {-1e30f, -1e30f, -1e30f, -1e30f};
#pragma unroll
  for (int j = 0; j < 5; ++j) {
    if (j < nst) {
      int sg = st[j] * 16 + lc;
#pragma unroll
      for (int r = 0; r < 4; ++r) {
        float v = sc[j][r] * 0.125f;
        if (sg >= 257) v = -1e30f;
        else if (q0 + lg * 4 + r == 0 && sg >= 1) v += pb[sg - 1];
        sc[j][r] = v;
        mx[r] = fmaxf(mx[r], v);
      }
    }
  }
#pragma unroll
  for (int r = 0; r < 4; ++r) {
    mx[r] = fmaxf(mx[r], __shfl_xor(mx[r], 1, 64));
    mx[r] = fmaxf(mx[r], __shfl_xor(mx[r], 2, 64));
    mx[r] = fmaxf(mx[r], __shfl_xor(mx[r], 4, 64));
    mx[r] = fmaxf(mx[r], __shfl_xor(mx[r], 8, 64));
  }
  __shared__ float smax[4][16];
  __shared__ float sden[4][16];
  __shared__ __align__(16) unsigned short P[16][SPAD];
  if (lc == 0) {
#pragma unroll
    for (int r = 0; r < 4; ++r) smax[wave][lg * 4 + r] = mx[r];
  }
  __syncthreads();
  float fm[4], den[4] = {0, 0, 0, 0};
#pragma unroll
  for (int r = 0; r < 4; ++r) {
    int qq = lg * 4 + r;
    fm[r] = fmaxf(fmaxf(smax[0][qq], smax[1][qq]), fmaxf(smax[2][qq], smax[3][qq]));
  }
#pragma unroll
  for (int j = 0; j < 5; ++j) {
    if (j < nst) {
#pragma unroll
      for (int r = 0; r < 4; ++r) {
        float pe = __expf(sc[j][r] - fm[r]);
        sc[j][r] = pe;
        den[r] += pe;
      }
    }
  }
#pragma unroll
  for (int r = 0; r < 4; ++r) {
    den[r] += __shfl_xor(den[r], 1, 64);
    den[r] += __shfl_xor(den[r], 2, 64);
    den[r] += __shfl_xor(den[r], 4, 64);
    den[r] += __shfl_xor(den[r], 8, 64);
  }
  if (lc == 0) {
#pragma unroll
    for (int r = 0; r < 4; ++r) sden[wave][lg * 4 + r] = den[r];
  }
  P[tid >> 4][272 + (tid & 15)] = 0;
#pragma unroll
  for (int j = 0; j < 5; ++j) {
    if (j < nst) {
#pragma unroll
      for (int r = 0; r < 4; ++r) P[lg * 4 + r][st[j] * 16 + lc] = f2bf(sc[j][r]);
    }
  }
  __syncthreads();
  float denf[4];
#pragma unroll
  for (int r = 0; r < 4; ++r) {
    int qq = lg * 4 + r;
    denf[r] = sden[0][qq] + sden[1][qq] + sden[2][qq] + sden[3][qq];
  }
  int d0 = wave * 16;
  float4_t oa = {0, 0, 0, 0};
#pragma unroll
  for (int s9 = 0; s9 < 9; ++s9) {
    short8 pa = *(const short8*)(&P[lc][s9 * 32 + lg * 8]);
    short8 bv = *(const short8*)(vh + (size_t)(d0 + lc) * SPAD + s9 * 32 + lg * 8);
    oa = MFMAs(pa, bv, oa);
  }
#pragma unroll
  for (int r = 0; r < 4; ++r) {
    int qg = q0 + lg * 4 + r;
    ob[(size_t)qg * E_DIM + head * 64 + d0 + lc] = f2bf(oa[r] / denf[r]);
  }
}

// ---------------------------------------------------------------------------
// reduce_ln
// ---------------------------------------------------------------------------
__global__ __launch_bounds__(256) void reduce_ln_kernel(
    float* __restrict__ x, const float* __restrict__ part, int nparts,
    const float* __restrict__ rbias,
    const float* __restrict__ lns, const float* __restrict__ lnb,
    unsigned short* __restrict__ hout) {
  int m = blockIdx.x, tid = threadIdx.x;
  int c0 = tid * 4;
  float4_t v = *(const float4_t*)(x + (size_t)m * E_DIM + c0);
  if (rbias) v += *(const float4_t*)(rbias + c0);
  for (int s = 0; s < nparts; ++s)
    v += *(const float4_t*)(part + ((size_t)s * MPAD + m) * E_DIM + c0);
  if (nparts > 0) *(float4_t*)(x + (size_t)m * E_DIM + c0) = v;
  float s1 = v[0] + v[1] + v[2] + v[3];
  float s2 = v[0] * v[0] + v[1] * v[1] + v[2] * v[2] + v[3] * v[3];
#pragma unroll
  for (int off = 1; off < 64; off <<= 1) {
    s1 += __shfl_xor(s1, off, 64);
    s2 += __shfl_xor(s2, off, 64);
  }
  __shared__ float red[8];
  int wave = tid >> 6, lane = tid & 63;
  if (lane == 0) { red[wave * 2] = s1; red[wave * 2 + 1] = s2; }
  __syncthreads();
  s1 = red[0] + red[2] + red[4] + red[6];
  s2 = red[1] + red[3] + red[5] + red[7];
  float mean = s1 * (1.f / 1024.f);
  float var = s2 * (1.f / 1024.f) - mean * mean;
  float rstd = rsqrtf(var + 1e-5f);
  float4_t ls = *(const float4_t*)(lns + c0);
  float4_t lb = *(const float4_t*)(lnb + c0);
  ushort4_t hv;
#pragma unroll
  for (int r = 0; r < 4; ++r) hv[r] = f2bf((v[r] - mean) * rstd * ls[r] + lb[r]);
  *(ushort4_t*)(hout + (size_t)m * E_DIM + c0) = hv;
}

// ---------------------------------------------------------------------------
// ROI pool
// ---------------------------------------------------------------------------
__global__ __launch_bounds__(256) void roi_kernel(const float* __restrict__ x,
                                                  const float* __restrict__ Mi,
                                                  float* __restrict__ out) {
  int b = blockIdx.x, tid = threadIdx.x;
  int c0 = tid * 4;
  if (b == 0) {
    *(float4_t*)(out + c0) = *(const float4_t*)(x + c0);
  } else {
    __shared__ float mi[256];
    mi[tid] = Mi[(b - 1) * 256 + tid];
    __syncthreads();
    float4_t acc = {0, 0, 0, 0};
    for (int p = 0; p < 256; ++p) {
      float4_t xv = *(const float4_t*)(x + (size_t)(1 + p) * E_DIM + c0);
      acc += mi[p] * xv;
    }
    *(float4_t*)(out + (size_t)b * E_DIM + c0) = acc;
  }
}

// ---------------------------------------------------------------------------
extern "C" void kernel_launch(void* const* d_in, const int* in_sizes, int n_in,
                              void* d_out, int out_size, void* d_ws, size_t ws_size,
                              hipStream_t stream) {
  const float* frame   = (const float*)d_in[0];
  const float* bboxes  = (const float*)d_in[1];
  const float* conv_w  = (const float*)d_in[2];
  const float* cls_emb = (const float*)d_in[3];
  const float* ln1_s   = (const float*)d_in[4];
  const float* ln1_b   = (const float*)d_in[5];
  const float* wq = (const float*)d_in[6];
  const float* bq = (const float*)d_in[7];
  const float* wk = (const float*)d_in[8];
  const float* bk = (const float*)d_in[9];
  const float* wv = (const float*)d_in[10];
  const float* bv = (const float*)d_in[11];
  const float* wo = (const float*)d_in[12];
  const float* bo = (const float*)d_in[13];
  const float* ln2_s = (const float*)d_in[14];
  const float* ln2_b = (const float*)d_in[15];
  const float* w1 = (const float*)d_in[16];
  const float* b1 = (const float*)d_in[17];
  const float* w2 = (const float*)d_in[18];
  const float* b2 = (const float*)d_in[19];

  char* base = (char*)d_ws;
  auto carve = [&](size_t bytes) {
    char* r = base;
    base += (bytes + 255) & ~(size_t)255;
    return r;
  };
  float* x            = (float*)carve((size_t)257 * E_DIM * 4);
  unsigned short* h   = (unsigned short*)carve((size_t)MPAD * E_DIM * 2);
  unsigned short* qb  = (unsigned short*)carve((size_t)16 * MPAD * 64 * 2);
  unsigned short* kbf = (unsigned short*)carve((size_t)16 * MPAD * 64 * 2);
  unsigned short* vTb = (unsigned short*)carve((size_t)16 * 64 * SPAD * 2);
  unsigned short* ob  = (unsigned short*)carve((size_t)MPAD * E_DIM * 2);
  unsigned short* mb  = (unsigned short*)carve((size_t)MPAD * FF_DIM * 2);
  float* part         = (float*)carve((size_t)4 * MPAD * E_DIM * 4);
  float* pbv          = (float*)carve(256 * 4);
  float* Mi           = (float*)carve(32 * 256 * 4);
  unsigned short* Pm  = (unsigned short*)carve((size_t)256 * KCP * 2);
  unsigned short* Wp  = (unsigned short*)carve((size_t)1024 * KCP * 2);

  prep_kernel<<<1280 + 1020, 256, 0, stream>>>(frame, conv_w, Pm, Wp, h, ob, vTb);
  pb_cls_kernel<<<1, 256, 0, stream>>>(bboxes, cls_emb, pbv, Mi, x);
  conv_gemm<<<64, 256, 0, stream>>>(Pm, Wp, x);
  reduce_ln_kernel<<<257, 256, 0, stream>>>(x, nullptr, 0, nullptr, ln1_s, ln1_b, h);

  for (int l = 0; l < LAYERS; ++l) {
    size_t o2  = (size_t)l * E_DIM * E_DIM;
    size_t o1  = (size_t)l * E_DIM;
    size_t of1 = (size_t)l * E_DIM * FF_DIM;
    size_t ofb = (size_t)l * FF_DIM;
    // QKV: 96 N-slices x 2 M-halves = 192 blocks, K=1024 (8 tiles)
    gemm_nk<1024, 0, 8><<<192, 256, 0, stream>>>(h, E_DIM, wq + o2, wk + o2, wv + o2,
                                                 bq + o1, bk + o1, bv + o1,
                                                 96, qb, kbf, vTb, nullptr, nullptr);
    attn_kernel<<<272, 256, 0, stream>>>(qb, kbf, vTb, pbv, ob);
    // O-proj: 32 N x 2 Mh x KS4 (chunk 256 = 2 tiles) = 256 blocks -> partials
    gemm_nk<1024, 2, 2><<<256, 256, 0, stream>>>(ob, E_DIM, wo + o2, nullptr, nullptr,
                                                 nullptr, nullptr, nullptr,
                                                 32, nullptr, nullptr, nullptr, nullptr, part);
    reduce_ln_kernel<<<257, 256, 0, stream>>>(x, part, 4, bo + o1, ln2_s + o1, ln2_b + o1, h);
    // FF1: 128 N x 2 Mh = 256 blocks, K=1024 (8 tiles); fused bias+quickgelu
    gemm_nk<4096, 1, 8><<<256, 256, 0, stream>>>(h, E_DIM, w1 + of1, nullptr, nullptr,
                                                 b1 + ofb, nullptr, nullptr,
                                                 128, nullptr, nullptr, nullptr, mb, nullptr);
    // FF2: 32 N x 2 Mh x KS4 (chunk 1024 = 8 tiles) = 256 blocks -> partials
    gemm_nk<1024, 2, 8><<<256, 256, 0, stream>>>(mb, FF_DIM, w2 + of1, nullptr, nullptr,
                                                 nullptr, nullptr, nullptr,
                                                 32, nullptr, nullptr, nullptr, nullptr, part);
    const float* nls = (l < LAYERS - 1) ? (ln1_s + (size_t)(l + 1) * E_DIM) : ln1_s;
    const float* nlb = (l < LAYERS - 1) ? (ln1_b + (size_t)(l + 1) * E_DIM) : ln1_b;
    reduce_ln_kernel<<<257, 256, 0, stream>>>(x, part, 4, b2 + o1, nls, nlb, h);
  }
  roi_kernel<<<33, 256, 0, stream>>>(x, Mi, (float*)d_out);
}